// Round 1
// baseline (1119.538 us; speedup 1.0000x reference)
//
#include <hip/hip_runtime.h>
#include <hip/hip_bf16.h>
#include <math.h>

#define G_HID 16
#define S_HID 10
#define D 128
#define MAX_STEP 4
#define NEG 0.01f
#define SCAN_TILE 1024
#define EMB_NODES 8
#define SN 64

__device__ __forceinline__ float leaky_f(float v){ return v >= 0.f ? v : NEG*v; }

// ---------------- prep: A, z-chain, transposed zT[step][g][k][s] ----------------
__global__ void prep_kernel(const float* __restrict__ hidden_adj,   // [16][45]
                            const float* __restrict__ hidden_feat,  // [16][10][128]
                            float* __restrict__ zT)                 // [4][16][128][10]
{
    int g = blockIdx.x;
    __shared__ float Ag[S_HID][S_HID];
    __shared__ float zb[2][S_HID][D];
    int t = threadIdx.x;
    if (t < S_HID*S_HID) {
        int i = t / S_HID, j = t % S_HID;
        float v = 0.f;
        if (i < j) {
            int idx = 9*i - i*(i-1)/2 + (j - i - 1);
            v = leaky_f(hidden_adj[g*45 + idx]);
        } else if (i > j) {
            int idx = 9*j - j*(j-1)/2 + (i - j - 1);
            v = leaky_f(hidden_adj[g*45 + idx]);
        }
        Ag[i][j] = v;
    }
    for (int idx = t; idx < S_HID*D; idx += blockDim.x) {
        int s = idx / D, d = idx % D;
        zb[0][s][d] = hidden_feat[(g*S_HID + s)*D + d];
    }
    __syncthreads();
    int cur = 0;
    for (int step = 0; step < MAX_STEP; ++step) {
        if (step > 0) {
            int nxt = cur ^ 1;
            for (int idx = t; idx < S_HID*D; idx += blockDim.x) {
                int s = idx / D, d = idx % D;
                float acc = 0.f;
                #pragma unroll
                for (int u = 0; u < S_HID; ++u) acc += Ag[s][u] * zb[cur][u][d];
                zb[nxt][s][d] = acc;
            }
            cur = nxt;
            __syncthreads();
        }
        for (int idx = t; idx < S_HID*D; idx += blockDim.x) {
            int s = idx / D, k = idx % D;
            zT[(((size_t)step*G_HID + g)*D + k)*S_HID + s] = zb[cur][s][k];
        }
    }
}

// ---------------- x0 = sigmoid(emb[x_idx] @ W + b) ----------------
__global__ void embed_linear_kernel(const int* __restrict__ x_idx,
                                    const float* __restrict__ poi_emb,
                                    const float* __restrict__ fc_w,   // [128][128]
                                    const float* __restrict__ fc_b,
                                    float* __restrict__ x0, int N)
{
    __shared__ float rows[EMB_NODES][D+4];
    int n0 = blockIdx.x * EMB_NODES;
    int t = threadIdx.x;  // 256
    for (int idx = t; idx < EMB_NODES*D; idx += 256) {
        int n = idx >> 7, k = idx & 127;
        int gn = n0 + n;
        float v = 0.f;
        if (gn < N) v = poi_emb[(size_t)x_idx[gn]*D + k];
        rows[n][k] = v;
    }
    __syncthreads();
    int n = t >> 5;          // 0..7
    int c4 = (t & 31) * 4;   // 0..124
    int gn = n0 + n;
    if (gn >= N) return;
    float4 acc = make_float4(0.f,0.f,0.f,0.f);
    for (int k = 0; k < D; ++k) {
        float xv = rows[n][k];
        float4 w = *reinterpret_cast<const float4*>(&fc_w[k*D + c4]);
        acc.x += xv*w.x; acc.y += xv*w.y; acc.z += xv*w.z; acc.w += xv*w.w;
    }
    float4 b = *reinterpret_cast<const float4*>(&fc_b[c4]);
    float4 o;
    o.x = 1.f/(1.f + __expf(-(acc.x + b.x)));
    o.y = 1.f/(1.f + __expf(-(acc.y + b.y)));
    o.z = 1.f/(1.f + __expf(-(acc.z + b.z)));
    o.w = 1.f/(1.f + __expf(-(acc.w + b.w)));
    *reinterpret_cast<float4*>(&x0[(size_t)gn*D + c4]) = o;
}

// ---------------- CSR build ----------------
__global__ void count_kernel(const int* __restrict__ dst, int* __restrict__ offsets, int E){
    int e = blockIdx.x*blockDim.x + threadIdx.x;
    if (e < E) atomicAdd(&offsets[dst[e]+1], 1);
}

__global__ void scan1_kernel(int* __restrict__ data, int* __restrict__ bsums, int n){
    __shared__ int wsum[4];
    int base = blockIdx.x * SCAN_TILE + threadIdx.x*4;
    int v[4];
    #pragma unroll
    for (int j=0;j<4;++j) v[j] = (base+j < n) ? data[base+j] : 0;
    v[1]+=v[0]; v[2]+=v[1]; v[3]+=v[2];
    int lane = threadIdx.x & 63;
    int w = threadIdx.x >> 6;
    int s = v[3];
    for (int d=1; d<64; d<<=1){
        int o = __shfl_up(s, d);
        if (lane >= d) s += o;
    }
    if (lane == 63) wsum[w] = s;
    int sexc = s - v[3];
    __syncthreads();
    int woff = 0;
    for (int ww=0; ww<w; ++ww) woff += wsum[ww];
    int off = woff + sexc;
    #pragma unroll
    for (int j=0;j<4;++j) { if (base+j < n) data[base+j] = v[j] + off; }
    if (threadIdx.x == 255) bsums[blockIdx.x] = off + v[3];
}

__global__ void scan2_kernel(int* __restrict__ bsums, int nb){
    __shared__ int ws[4];
    __shared__ int carry_s;
    if (threadIdx.x == 0) carry_s = 0;
    __syncthreads();
    for (int start = 0; start < nb; start += 256){
        int i = start + (int)threadIdx.x;
        int v = (i < nb) ? bsums[i] : 0;
        int lane = threadIdx.x & 63, w = threadIdx.x >> 6;
        int s = v;
        for (int d=1; d<64; d<<=1){ int o = __shfl_up(s, d); if (lane >= d) s += o; }
        if (lane == 63) ws[w] = s;
        __syncthreads();
        int woff = 0;
        for (int ww=0; ww<w; ++ww) woff += ws[ww];
        int inc = s + woff + carry_s;
        if (i < nb) bsums[i] = inc - v;
        __syncthreads();
        if (threadIdx.x == 255) carry_s = inc;
        __syncthreads();
    }
}

__global__ void scan3_kernel(int* __restrict__ data, const int* __restrict__ bsums, int n){
    int base = blockIdx.x * SCAN_TILE + threadIdx.x*4;
    int add = bsums[blockIdx.x];
    #pragma unroll
    for (int j=0;j<4;++j){ if (base+j < n) data[base+j] += add; }
}

__global__ void fill_kernel(const int* __restrict__ src, const int* __restrict__ dst,
                            const int* __restrict__ offsets, int* __restrict__ fillcnt,
                            int* __restrict__ csr, int E){
    int e = blockIdx.x*blockDim.x + threadIdx.x;
    if (e < E){
        int d = dst[e];
        int pos = atomicAdd(&fillcnt[d], 1);
        csr[offsets[d]+pos] = src[e];
    }
}

// ---------------- propagate: xout[v] = sum_{u->v} xin[u] ----------------
__global__ void prop_kernel(const float* __restrict__ xin, float* __restrict__ xout,
                            const int* __restrict__ offsets, const int* __restrict__ csr, int N){
    int wid = (blockIdx.x*blockDim.x + threadIdx.x) >> 6;
    int lane = threadIdx.x & 63;
    int v = __builtin_amdgcn_readfirstlane(wid);
    if (v >= N) return;
    int beg = __builtin_amdgcn_readfirstlane(offsets[v]);
    int end = __builtin_amdgcn_readfirstlane(offsets[v+1]);
    float a0 = 0.f, a1 = 0.f;
    for (int ei = beg; ei < end; ++ei){
        int u = __builtin_amdgcn_readfirstlane(csr[ei]);
        const float* r = xin + (size_t)u*D;
        a0 += r[lane];
        a1 += r[lane+64];
    }
    xout[(size_t)v*D + lane] = a0;
    xout[(size_t)v*D + 64 + lane] = a1;
}

// ---------------- per-step fused y + pooled ----------------
__global__ void step_kernel(const float* __restrict__ xin,   // [N][128]
                            const float* __restrict__ zTs,   // [16][128][10]
                            const int* __restrict__ batch,
                            float* __restrict__ y0buf,       // [16][N][10]
                            float* __restrict__ pooled,      // [B][64]
                            int N, int stepoff, int isStep0)
{
    __shared__ float xs[SN][D+1];
    __shared__ float accs[SN][G_HID];
    __shared__ int slots[SN];
    __shared__ int slotb[SN];
    __shared__ int nslots_s;
    int n0 = blockIdx.x * SN;
    int t = threadIdx.x;  // 256
    for (int idx = t; idx < SN*D; idx += 256) {
        int n = idx >> 7, k = idx & 127;
        int gn = n0 + n;
        xs[n][k] = (gn < N) ? xin[(size_t)gn*D + k] : 0.f;
    }
    for (int idx = t; idx < SN*G_HID; idx += 256) (&accs[0][0])[idx] = 0.f;
    if (t < 64) {
        int gn = n0 + t;
        int b = (gn < N) ? batch[gn] : -1;
        int bprev = -1;
        if (t > 0) bprev = (gn-1 < N) ? batch[gn-1] : -1;
        int flag = (t == 0 || b != bprev) ? 1 : 0;
        int s = flag;
        for (int d=1; d<64; d<<=1){ int o = __shfl_up(s, d); if (t >= d) s += o; }
        int slot = s - 1;
        slots[t] = slot;
        if (flag) slotb[slot] = b;
        if (t == 63) nslots_s = s;
    }
    __syncthreads();

    int lane = t & 63;
    int wv = t >> 6;
    int n = lane;
    int gn = n0 + n;
    bool valid = gn < N;
    for (int gi = 0; gi < 4; ++gi) {
        int g = __builtin_amdgcn_readfirstlane(wv*4 + gi);
        const float2* zg2 = reinterpret_cast<const float2*>(zTs + (size_t)g*(D*S_HID));
        float y[S_HID];
        #pragma unroll
        for (int s=0;s<S_HID;++s) y[s] = 0.f;
        #pragma unroll 2
        for (int k=0;k<D;++k){
            float xv = xs[n][k];
            #pragma unroll
            for (int j=0;j<5;++j){
                float2 z2 = zg2[k*5 + j];
                y[2*j]   += xv * z2.x;
                y[2*j+1] += xv * z2.y;
            }
        }
        float c = 0.f;
        size_t ybase = ((size_t)g*N + gn)*S_HID;
        if (isStep0) {
            #pragma unroll
            for (int s=0;s<S_HID;++s) c += y[s]*y[s];
            if (valid) {
                float2* yp = reinterpret_cast<float2*>(y0buf + ybase);
                #pragma unroll
                for (int j=0;j<5;++j) yp[j] = make_float2(y[2*j], y[2*j+1]);
            }
        } else if (valid) {
            const float2* yp = reinterpret_cast<const float2*>(y0buf + ybase);
            #pragma unroll
            for (int j=0;j<5;++j){
                float2 v2 = yp[j];
                c += y[2*j]*v2.x + y[2*j+1]*v2.y;
            }
        }
        if (valid) atomicAdd(&accs[slots[n]][g], c);
    }
    __syncthreads();
    int ns = nslots_s;
    for (int idx = t; idx < ns*G_HID; idx += 256) {
        int j = idx >> 4, g = idx & 15;
        int b = slotb[j];
        if (b >= 0) atomicAdd(&pooled[(size_t)b*64 + stepoff + g], accs[j][g]);
    }
}

// ---------------- out = leaky(pooled @ mlp_w + mlp_b) ----------------
__global__ void out_kernel(const float* __restrict__ pooled, const float* __restrict__ mlp_w,
                           const float* __restrict__ mlp_b, float* __restrict__ out, int B){
    __shared__ float row[64];
    int b = blockIdx.x;
    int t = threadIdx.x;  // 128
    if (t < 64) row[t] = pooled[(size_t)b*64 + t];
    __syncthreads();
    float acc = mlp_b[t];
    for (int j=0;j<64;++j) acc += row[j]*mlp_w[j*D + t];
    out[(size_t)b*D + t] = leaky_f(acc);
}

extern "C" void kernel_launch(void* const* d_in, const int* in_sizes, int n_in,
                              void* d_out, int out_size, void* d_ws, size_t ws_size,
                              hipStream_t stream)
{
    const int*   x_idx = (const int*)d_in[0];
    const int*   edge  = (const int*)d_in[1];
    const int*   batch = (const int*)d_in[2];
    const float* poi   = (const float*)d_in[3];
    const float* fc_w  = (const float*)d_in[4];
    const float* fc_b  = (const float*)d_in[5];
    const float* adj   = (const float*)d_in[6];
    const float* feat  = (const float*)d_in[7];
    const float* mlp_w = (const float*)d_in[8];
    const float* mlp_b = (const float*)d_in[9];
    float* out = (float*)d_out;

    int N = in_sizes[0];
    int E = in_sizes[1] / 2;
    int B = out_size / D;

    char* p = (char*)d_ws;
    auto alloc = [&](size_t bytes)->char* {
        char* r = p;
        p += (bytes + 255) & ~(size_t)255;
        return r;
    };
    float* x0     = (float*)alloc((size_t)N*D*4);
    float* xa     = (float*)alloc((size_t)N*D*4);
    float* xb     = (float*)alloc((size_t)N*D*4);
    float* y0buf  = (float*)alloc((size_t)G_HID*N*S_HID*4);
    float* pooled = (float*)alloc((size_t)B*64*4);
    float* zT     = (float*)alloc((size_t)MAX_STEP*G_HID*D*S_HID*4);
    int*   offsets= (int*)alloc((size_t)(N+1)*4);
    int*   fillcnt= (int*)alloc((size_t)N*4);
    int*   csr    = (int*)alloc((size_t)E*4);
    int*   bsums  = (int*)alloc(4096);

    const int* srcp = edge;
    const int* dstp = edge + E;

    hipMemsetAsync(offsets, 0, (size_t)(N+1)*4, stream);
    hipMemsetAsync(fillcnt, 0, (size_t)N*4, stream);
    hipMemsetAsync(pooled, 0, (size_t)B*64*4, stream);

    prep_kernel<<<G_HID, 256, 0, stream>>>(adj, feat, zT);
    embed_linear_kernel<<<(N + EMB_NODES-1)/EMB_NODES, 256, 0, stream>>>(x_idx, poi, fc_w, fc_b, x0, N);
    count_kernel<<<(E+255)/256, 256, 0, stream>>>(dstp, offsets, E);
    int scan_n = N + 1;
    int nblk = (scan_n + SCAN_TILE - 1) / SCAN_TILE;
    scan1_kernel<<<nblk, 256, 0, stream>>>(offsets, bsums, scan_n);
    scan2_kernel<<<1, 256, 0, stream>>>(bsums, nblk);
    scan3_kernel<<<nblk, 256, 0, stream>>>(offsets, bsums, scan_n);
    fill_kernel<<<(E+255)/256, 256, 0, stream>>>(srcp, dstp, offsets, fillcnt, csr, E);

    int sblk = (N + SN - 1) / SN;
    step_kernel<<<sblk, 256, 0, stream>>>(x0, zT, batch, y0buf, pooled, N, 0, 1);

    const float* xin = x0;
    float* bufs[2] = {xa, xb};
    for (int i = 1; i < MAX_STEP; ++i){
        float* xout = bufs[(i-1) & 1];
        prop_kernel<<<(N+3)/4, 256, 0, stream>>>(xin, xout, offsets, csr, N);
        step_kernel<<<sblk, 256, 0, stream>>>(xout, zT + (size_t)i*G_HID*D*S_HID, batch,
                                              y0buf, pooled, N, i*G_HID, 0);
        xin = xout;
    }
    out_kernel<<<B, D, 0, stream>>>(pooled, mlp_w, mlp_b, out, B);
}

// Round 2
// 371.543 us; speedup vs baseline: 3.0132x; 3.0132x over previous
//
#include <hip/hip_runtime.h>
#include <hip/hip_bf16.h>
#include <math.h>

#define G_HID 16
#define S_HID 10
#define D 128
#define MAX_STEP 4
#define NEG 0.01f
#define SCAN_TILE 1024

typedef __attribute__((ext_vector_type(8))) short short8;
typedef __attribute__((ext_vector_type(4))) float f32x4;

__device__ __forceinline__ float leaky_f(float v){ return v >= 0.f ? v : NEG*v; }
__device__ __forceinline__ unsigned short f2bf(float f){
    unsigned int u = __float_as_uint(f);
    u = (u + 0x7FFFu + ((u>>16)&1u)) >> 16;
    return (unsigned short)u;
}

// ---------------- prep: A, z-chain, pack z into MFMA A-fragment layout ----------------
// zpack[step][tile t (10)][kt (4)][lane (64)][j (8)]  (bf16 stored as short)
// A row = g*10+s in [0,160); row = t*16 + (lane&15); k = kt*32 + (lane>>4)*8 + j
__global__ void prep_kernel(const float* __restrict__ hidden_adj,   // [16][45]
                            const float* __restrict__ hidden_feat,  // [16][10][128]
                            short* __restrict__ zpack)
{
    int g = blockIdx.x;
    __shared__ float Ag[S_HID][S_HID];
    __shared__ float zb[2][S_HID][D];
    int t = threadIdx.x;  // 128
    if (t < S_HID*S_HID) {
        int i = t / S_HID, j = t % S_HID;
        float v = 0.f;
        if (i < j) {
            int idx = 9*i - i*(i-1)/2 + (j - i - 1);
            v = leaky_f(hidden_adj[g*45 + idx]);
        } else if (i > j) {
            int idx = 9*j - j*(j-1)/2 + (i - j - 1);
            v = leaky_f(hidden_adj[g*45 + idx]);
        }
        Ag[i][j] = v;
    }
    for (int idx = t; idx < S_HID*D; idx += 128) {
        int s = idx / D, d = idx % D;
        zb[0][s][d] = hidden_feat[(g*S_HID + s)*D + d];
    }
    __syncthreads();
    int cur = 0;
    for (int step = 0; step < MAX_STEP; ++step) {
        if (step > 0) {
            int nxt = cur ^ 1;
            for (int idx = t; idx < S_HID*D; idx += 128) {
                int s = idx / D, d = idx % D;
                float acc = 0.f;
                #pragma unroll
                for (int u = 0; u < S_HID; ++u) acc += Ag[s][u] * zb[cur][u][d];
                zb[nxt][s][d] = acc;
            }
            cur = nxt;
            __syncthreads();
        }
        for (int idx = t; idx < S_HID*D; idx += 128) {
            int s = idx / D, k = idx % D;
            int row = g*S_HID + s;
            int tt = row >> 4, li = row & 15;
            int kt = k >> 5, q = (k >> 3) & 3, j = k & 7;
            zpack[(((step*10 + tt)*4 + kt)*64 + q*16 + li)*8 + j] = (short)f2bf(zb[cur][s][k]);
        }
        __syncthreads();
    }
}

// ---------------- pack fc_w into MFMA B-fragment layout ----------------
// wp[kt (4)][ct (8)][lane (64)][j (8)]: B[k][col], k=kt*32+(lane>>4)*8+j, col=ct*16+(lane&15)
__global__ void wpack_kernel(const float* __restrict__ fc_w, short* __restrict__ wp){
    int idx = blockIdx.x*256 + threadIdx.x;
    if (idx >= 16384) return;
    int j = idx & 7, lane = (idx >> 3) & 63, ctkt = idx >> 9;
    int ct = ctkt & 7, kt = ctkt >> 3;
    int k   = kt*32 + (lane >> 4)*8 + j;
    int col = ct*16 + (lane & 15);
    wp[idx] = (short)f2bf(fc_w[k*D + col]);
}

// ---------------- x0 = sigmoid(emb[x_idx] @ W + b), MFMA, bf16 out ----------------
__global__ __launch_bounds__(256) void embed_mfma_kernel(const int* __restrict__ x_idx,
                                    const float* __restrict__ poi_emb,
                                    const short* __restrict__ wp,
                                    const float* __restrict__ fc_b,
                                    unsigned short* __restrict__ x0, int N)
{
    __shared__ __align__(16) unsigned short emb[64*136];  // 64 rows, pitch 136 bf16
    int n0 = blockIdx.x * 64;
    int t = threadIdx.x;  // 256
    #pragma unroll
    for (int i = 0; i < 8; ++i) {
        int idx = t + i*256;
        int row = idx >> 5, c4 = (idx & 31)*4;
        int gn = n0 + row;
        float4 v = make_float4(0.f,0.f,0.f,0.f);
        if (gn < N) v = *reinterpret_cast<const float4*>(&poi_emb[(size_t)x_idx[gn]*D + c4]);
        unsigned int p0 = (unsigned int)f2bf(v.x) | ((unsigned int)f2bf(v.y) << 16);
        unsigned int p1 = (unsigned int)f2bf(v.z) | ((unsigned int)f2bf(v.w) << 16);
        *reinterpret_cast<uint2*>(&emb[row*136 + c4]) = make_uint2(p0, p1);
    }
    __syncthreads();
    int l = t & 63, w = t >> 6, li = l & 15, q = l >> 4;
    short8 a[4];
    #pragma unroll
    for (int kt = 0; kt < 4; ++kt)
        a[kt] = *reinterpret_cast<const short8*>(&emb[(w*16 + li)*136 + kt*32 + q*8]);
    f32x4 acc[8];
    #pragma unroll
    for (int ct = 0; ct < 8; ++ct) acc[ct] = (f32x4){0.f,0.f,0.f,0.f};
    #pragma unroll
    for (int kt = 0; kt < 4; ++kt){
        #pragma unroll
        for (int ct = 0; ct < 8; ++ct){
            short8 b = reinterpret_cast<const short8*>(wp)[(kt*8 + ct)*64 + l];
            acc[ct] = __builtin_amdgcn_mfma_f32_16x16x32_bf16(a[kt], b, acc[ct], 0, 0, 0);
        }
    }
    __syncthreads();
    #pragma unroll
    for (int ct = 0; ct < 8; ++ct){
        float bias = fc_b[ct*16 + li];
        #pragma unroll
        for (int r = 0; r < 4; ++r){
            float v = acc[ct][r] + bias;
            float s = 1.f/(1.f + __expf(-v));
            emb[(w*16 + q*4 + r)*136 + ct*16 + li] = f2bf(s);
        }
    }
    __syncthreads();
    int row = t >> 2, ch = t & 3, gn = n0 + row;
    if (gn < N){
        #pragma unroll
        for (int i2 = 0; i2 < 4; ++i2){
            uint4 v = *reinterpret_cast<const uint4*>(&emb[row*136 + ch*32 + i2*8]);
            *reinterpret_cast<uint4*>(&x0[(size_t)gn*D + ch*32 + i2*8]) = v;
        }
    }
}

// ---------------- CSR build ----------------
__global__ void count_kernel(const int* __restrict__ dst, int* __restrict__ offsets, int E){
    int e = blockIdx.x*blockDim.x + threadIdx.x;
    if (e < E) atomicAdd(&offsets[dst[e]+1], 1);
}

__global__ void scan1_kernel(int* __restrict__ data, int* __restrict__ bsums, int n){
    __shared__ int wsum[4];
    int base = blockIdx.x * SCAN_TILE + threadIdx.x*4;
    int v[4];
    #pragma unroll
    for (int j=0;j<4;++j) v[j] = (base+j < n) ? data[base+j] : 0;
    v[1]+=v[0]; v[2]+=v[1]; v[3]+=v[2];
    int lane = threadIdx.x & 63;
    int w = threadIdx.x >> 6;
    int s = v[3];
    for (int d=1; d<64; d<<=1){
        int o = __shfl_up(s, d);
        if (lane >= d) s += o;
    }
    if (lane == 63) wsum[w] = s;
    int sexc = s - v[3];
    __syncthreads();
    int woff = 0;
    for (int ww=0; ww<w; ++ww) woff += wsum[ww];
    int off = woff + sexc;
    #pragma unroll
    for (int j=0;j<4;++j) { if (base+j < n) data[base+j] = v[j] + off; }
    if (threadIdx.x == 255) bsums[blockIdx.x] = off + v[3];
}

__global__ void scan2_kernel(int* __restrict__ bsums, int nb){
    __shared__ int ws[4];
    __shared__ int carry_s;
    if (threadIdx.x == 0) carry_s = 0;
    __syncthreads();
    for (int start = 0; start < nb; start += 256){
        int i = start + (int)threadIdx.x;
        int v = (i < nb) ? bsums[i] : 0;
        int lane = threadIdx.x & 63, w = threadIdx.x >> 6;
        int s = v;
        for (int d=1; d<64; d<<=1){ int o = __shfl_up(s, d); if (lane >= d) s += o; }
        if (lane == 63) ws[w] = s;
        __syncthreads();
        int woff = 0;
        for (int ww=0; ww<w; ++ww) woff += ws[ww];
        int inc = s + woff + carry_s;
        if (i < nb) bsums[i] = inc - v;
        __syncthreads();
        if (threadIdx.x == 255) carry_s = inc;
        __syncthreads();
    }
}

__global__ void scan3_kernel(int* __restrict__ data, const int* __restrict__ bsums, int n){
    int base = blockIdx.x * SCAN_TILE + threadIdx.x*4;
    int add = bsums[blockIdx.x];
    #pragma unroll
    for (int j=0;j<4;++j){ if (base+j < n) data[base+j] += add; }
}

__global__ void fill_kernel(const int* __restrict__ src, const int* __restrict__ dst,
                            const int* __restrict__ offsets, int* __restrict__ fillcnt,
                            int* __restrict__ csr, int E){
    int e = blockIdx.x*blockDim.x + threadIdx.x;
    if (e < E){
        int d = dst[e];
        int pos = atomicAdd(&fillcnt[d], 1);
        csr[offsets[d]+pos] = src[e];
    }
}

// ---------------- propagate (bf16): xout[v] = sum_{u->v} xin[u] ----------------
__global__ __launch_bounds__(256) void prop_kernel(const unsigned short* __restrict__ xin,
                            unsigned short* __restrict__ xout,
                            const int* __restrict__ offsets, const int* __restrict__ csr, int N){
    int wid = (blockIdx.x*256 + threadIdx.x) >> 6;
    int lane = threadIdx.x & 63;
    int v = __builtin_amdgcn_readfirstlane(wid);
    if (v >= N) return;
    int beg = __builtin_amdgcn_readfirstlane(offsets[v]);
    int end = __builtin_amdgcn_readfirstlane(offsets[v+1]);
    float a0 = 0.f, a1 = 0.f;
    const unsigned int* xi = (const unsigned int*)xin;
    for (int ei = beg; ei < end; ++ei){
        int u = __builtin_amdgcn_readfirstlane(csr[ei]);
        unsigned int pv = xi[(size_t)u*64 + lane];
        a0 += __uint_as_float(pv << 16);
        a1 += __uint_as_float(pv & 0xFFFF0000u);
    }
    ((unsigned int*)xout)[(size_t)v*64 + lane] =
        (unsigned int)f2bf(a0) | ((unsigned int)f2bf(a1) << 16);
}

// ---------------- per-step fused: Y = Z @ X^T (MFMA) -> *y0 -> pooled ----------------
template<int STEP0>
__global__ __launch_bounds__(256) void step_mfma_kernel(const unsigned short* __restrict__ x,
                                 const short* __restrict__ zstep,   // [10][4][64][8] bf16
                                 const int* __restrict__ batch,
                                 float4* __restrict__ y0buf,        // [blk][w][10][64] float4
                                 float* __restrict__ pooled,        // [B][64]
                                 int N, int stepoff)
{
    __shared__ __align__(16) char lbuf[42240];   // z (40960B) then reused as P[160][66] f32
    __shared__ float accs[64][G_HID];
    __shared__ int slots[64];
    __shared__ int slotb[64];
    __shared__ int nslots_s;
    short* zls = (short*)lbuf;
    float* Pf  = (float*)lbuf;
    int n0 = blockIdx.x * 64;
    int t = threadIdx.x;  // 256

    #pragma unroll
    for (int i = 0; i < 10; ++i)
        ((uint4*)lbuf)[t + i*256] = ((const uint4*)zstep)[t + i*256];
    #pragma unroll
    for (int i = 0; i < 4; ++i) ((float*)accs)[t + i*256] = 0.f;
    if (t < 64) {
        int gn = n0 + t;
        int b = (gn < N) ? batch[gn] : -1;
        int bprev = -1;
        if (t > 0) bprev = (gn-1 < N) ? batch[gn-1] : -1;
        int flag = (t == 0 || b != bprev) ? 1 : 0;
        int s = flag;
        for (int d=1; d<64; d<<=1){ int o = __shfl_up(s, d); if (t >= d) s += o; }
        int slot = s - 1;
        slots[t] = slot;
        if (flag) slotb[slot] = b;
        if (t == 63) nslots_s = s;
    }
    __syncthreads();

    int l = t & 63, w = t >> 6, li = l & 15, q = l >> 4;
    int node = n0 + w*16 + li;
    bool valid = node < N;
    short8 bw[4];
    #pragma unroll
    for (int kt = 0; kt < 4; ++kt){
        if (valid) bw[kt] = *reinterpret_cast<const short8*>(&x[(size_t)node*D + kt*32 + q*8]);
        else       bw[kt] = (short8){0,0,0,0,0,0,0,0};
    }
    f32x4 accA[10];
    #pragma unroll
    for (int t10 = 0; t10 < 10; ++t10){
        f32x4 acc = (f32x4){0.f,0.f,0.f,0.f};
        #pragma unroll
        for (int kt = 0; kt < 4; ++kt){
            short8 az = *reinterpret_cast<const short8*>(&zls[((t10*4 + kt)*64 + l)*8]);
            acc = __builtin_amdgcn_mfma_f32_16x16x32_bf16(az, bw[kt], acc, 0, 0, 0);
        }
        accA[t10] = acc;
    }
    __syncthreads();   // done reading zls; reuse as P

    size_t ybase = ((size_t)blockIdx.x*4 + w)*10*64 + l;
    #pragma unroll
    for (int t10 = 0; t10 < 10; ++t10){
        f32x4 acc = accA[t10];
        float p0, p1, p2, p3;
        if (STEP0){
            float4 st; st.x = acc[0]; st.y = acc[1]; st.z = acc[2]; st.w = acc[3];
            y0buf[ybase + (size_t)t10*64] = st;
            p0 = acc[0]*acc[0]; p1 = acc[1]*acc[1]; p2 = acc[2]*acc[2]; p3 = acc[3]*acc[3];
        } else {
            float4 y0 = y0buf[ybase + (size_t)t10*64];
            p0 = acc[0]*y0.x; p1 = acc[1]*y0.y; p2 = acc[2]*y0.z; p3 = acc[3]*y0.w;
        }
        int rb = (t10*16 + q*4)*66 + w*16 + li;
        Pf[rb]       = p0;
        Pf[rb + 66]  = p1;
        Pf[rb + 132] = p2;
        Pf[rb + 198] = p3;
    }
    __syncthreads();

    #pragma unroll
    for (int i = 0; i < 4; ++i){
        int g = t & 15, nd = (t >> 4) + i*16;
        float c = 0.f;
        #pragma unroll
        for (int s = 0; s < S_HID; ++s) c += Pf[(g*10 + s)*66 + nd];
        atomicAdd(&accs[slots[nd]][g], c);
    }
    __syncthreads();
    int ns = nslots_s;
    for (int idx = t; idx < ns*G_HID; idx += 256){
        int j = idx >> 4, g = idx & 15;
        int b = slotb[j];
        if (b >= 0) atomicAdd(&pooled[(size_t)b*64 + stepoff + g], accs[j][g]);
    }
}

// ---------------- out = leaky(pooled @ mlp_w + mlp_b) ----------------
__global__ void out_kernel(const float* __restrict__ pooled, const float* __restrict__ mlp_w,
                           const float* __restrict__ mlp_b, float* __restrict__ out, int B){
    __shared__ float row[64];
    int b = blockIdx.x;
    int t = threadIdx.x;  // 128
    if (t < 64) row[t] = pooled[(size_t)b*64 + t];
    __syncthreads();
    float acc = mlp_b[t];
    for (int j=0;j<64;++j) acc += row[j]*mlp_w[j*D + t];
    out[(size_t)b*D + t] = leaky_f(acc);
}

extern "C" void kernel_launch(void* const* d_in, const int* in_sizes, int n_in,
                              void* d_out, int out_size, void* d_ws, size_t ws_size,
                              hipStream_t stream)
{
    const int*   x_idx = (const int*)d_in[0];
    const int*   edge  = (const int*)d_in[1];
    const int*   batch = (const int*)d_in[2];
    const float* poi   = (const float*)d_in[3];
    const float* fc_w  = (const float*)d_in[4];
    const float* fc_b  = (const float*)d_in[5];
    const float* adj   = (const float*)d_in[6];
    const float* feat  = (const float*)d_in[7];
    const float* mlp_w = (const float*)d_in[8];
    const float* mlp_b = (const float*)d_in[9];
    float* out = (float*)d_out;

    int N = in_sizes[0];
    int E = in_sizes[1] / 2;
    int B = out_size / D;
    int sblk = (N + 63) / 64;
    size_t NP = (size_t)sblk * 64;

    char* p = (char*)d_ws;
    auto alloc = [&](size_t bytes)->char* {
        char* r = p;
        p += (bytes + 255) & ~(size_t)255;
        return r;
    };
    unsigned short* x0 = (unsigned short*)alloc(NP*D*2);
    unsigned short* xa = (unsigned short*)alloc(NP*D*2);
    unsigned short* xb = (unsigned short*)alloc(NP*D*2);
    float4* y0buf      = (float4*)alloc(NP*160*4);          // fp32 zx in fragment layout
    float* pooled      = (float*)alloc((size_t)B*64*4);
    short* zpack       = (short*)alloc((size_t)MAX_STEP*20480*2);
    short* wp          = (short*)alloc((size_t)16384*2);
    int*   offsets     = (int*)alloc((size_t)(N+1)*4);
    int*   fillcnt     = (int*)alloc((size_t)N*4);
    int*   csr         = (int*)alloc((size_t)E*4);
    int*   bsums       = (int*)alloc(4096);

    const int* srcp = edge;
    const int* dstp = edge + E;

    hipMemsetAsync(offsets, 0, (size_t)(N+1)*4, stream);
    hipMemsetAsync(fillcnt, 0, (size_t)N*4, stream);
    hipMemsetAsync(pooled, 0, (size_t)B*64*4, stream);

    prep_kernel<<<G_HID, 128, 0, stream>>>(adj, feat, zpack);
    wpack_kernel<<<64, 256, 0, stream>>>(fc_w, wp);
    embed_mfma_kernel<<<sblk, 256, 0, stream>>>(x_idx, poi, wp, fc_b, x0, N);

    count_kernel<<<(E+255)/256, 256, 0, stream>>>(dstp, offsets, E);
    int scan_n = N + 1;
    int nblk = (scan_n + SCAN_TILE - 1) / SCAN_TILE;
    scan1_kernel<<<nblk, 256, 0, stream>>>(offsets, bsums, scan_n);
    scan2_kernel<<<1, 256, 0, stream>>>(bsums, nblk);
    scan3_kernel<<<nblk, 256, 0, stream>>>(offsets, bsums, scan_n);
    fill_kernel<<<(E+255)/256, 256, 0, stream>>>(srcp, dstp, offsets, fillcnt, csr, E);

    step_mfma_kernel<1><<<sblk, 256, 0, stream>>>(x0, zpack, batch, y0buf, pooled, N, 0);

    const unsigned short* xin = x0;
    unsigned short* bufs[2] = {xa, xb};
    for (int i = 1; i < MAX_STEP; ++i){
        unsigned short* xout = bufs[(i-1) & 1];
        prop_kernel<<<(N+3)/4, 256, 0, stream>>>(xin, xout, offsets, csr, N);
        step_mfma_kernel<0><<<sblk, 256, 0, stream>>>(xout, zpack + (size_t)i*20480, batch,
                                                      y0buf, pooled, N, i*G_HID);
        xin = xout;
    }
    out_kernel<<<B, D, 0, stream>>>(pooled, mlp_w, mlp_b, out, B);
}

// Round 3
// 323.817 us; speedup vs baseline: 3.4573x; 1.1474x over previous
//
#include <hip/hip_runtime.h>
#include <hip/hip_bf16.h>
#include <math.h>

#define G_HID 16
#define S_HID 10
#define D 128
#define MAX_STEP 4
#define NEG 0.01f
#define SCAN_TILE 1024

typedef __attribute__((ext_vector_type(8))) short short8;
typedef __attribute__((ext_vector_type(4))) float f32x4;

__device__ __forceinline__ float leaky_f(float v){ return v >= 0.f ? v : NEG*v; }
__device__ __forceinline__ unsigned short f2bf(float f){
    unsigned int u = __float_as_uint(f);
    u = (u + 0x7FFFu + ((u>>16)&1u)) >> 16;
    return (unsigned short)u;
}
__device__ __forceinline__ float bf_lo(unsigned int v){ return __uint_as_float(v << 16); }
__device__ __forceinline__ float bf_hi(unsigned int v){ return __uint_as_float(v & 0xFFFF0000u); }

// ---------------- prep: A, z-chain, pack z into MFMA A-fragment layout ----------------
__global__ void prep_kernel(const float* __restrict__ hidden_adj,   // [16][45]
                            const float* __restrict__ hidden_feat,  // [16][10][128]
                            short* __restrict__ zpack)
{
    int g = blockIdx.x;
    __shared__ float Ag[S_HID][S_HID];
    __shared__ float zb[2][S_HID][D];
    int t = threadIdx.x;  // 128
    if (t < S_HID*S_HID) {
        int i = t / S_HID, j = t % S_HID;
        float v = 0.f;
        if (i < j) {
            int idx = 9*i - i*(i-1)/2 + (j - i - 1);
            v = leaky_f(hidden_adj[g*45 + idx]);
        } else if (i > j) {
            int idx = 9*j - j*(j-1)/2 + (i - j - 1);
            v = leaky_f(hidden_adj[g*45 + idx]);
        }
        Ag[i][j] = v;
    }
    for (int idx = t; idx < S_HID*D; idx += 128) {
        int s = idx / D, d = idx % D;
        zb[0][s][d] = hidden_feat[(g*S_HID + s)*D + d];
    }
    __syncthreads();
    int cur = 0;
    for (int step = 0; step < MAX_STEP; ++step) {
        if (step > 0) {
            int nxt = cur ^ 1;
            for (int idx = t; idx < S_HID*D; idx += 128) {
                int s = idx / D, d = idx % D;
                float acc = 0.f;
                #pragma unroll
                for (int u = 0; u < S_HID; ++u) acc += Ag[s][u] * zb[cur][u][d];
                zb[nxt][s][d] = acc;
            }
            cur = nxt;
            __syncthreads();
        }
        for (int idx = t; idx < S_HID*D; idx += 128) {
            int s = idx / D, k = idx % D;
            int row = g*S_HID + s;
            int tt = row >> 4, li = row & 15;
            int kt = k >> 5, q = (k >> 3) & 3, j = k & 7;
            zpack[(((step*10 + tt)*4 + kt)*64 + q*16 + li)*8 + j] = (short)f2bf(zb[cur][s][k]);
        }
        __syncthreads();
    }
}

// ---------------- pack fc_w into MFMA B-fragment layout ----------------
__global__ void wpack_kernel(const float* __restrict__ fc_w, short* __restrict__ wp){
    int idx = blockIdx.x*256 + threadIdx.x;
    if (idx >= 16384) return;
    int j = idx & 7, lane = (idx >> 3) & 63, ctkt = idx >> 9;
    int ct = ctkt & 7, kt = ctkt >> 3;
    int k   = kt*32 + (lane >> 4)*8 + j;
    int col = ct*16 + (lane & 15);
    wp[idx] = (short)f2bf(fc_w[k*D + col]);
}

// ---------------- x0 = sigmoid(emb[x_idx] @ W + b), MFMA, bf16 out ----------------
__global__ __launch_bounds__(256) void embed_mfma_kernel(const int* __restrict__ x_idx,
                                    const float* __restrict__ poi_emb,
                                    const short* __restrict__ wp,
                                    const float* __restrict__ fc_b,
                                    unsigned short* __restrict__ x0, int N)
{
    __shared__ __align__(16) unsigned short emb[64*136];
    int n0 = blockIdx.x * 64;
    int t = threadIdx.x;  // 256
    #pragma unroll
    for (int i = 0; i < 8; ++i) {
        int idx = t + i*256;
        int row = idx >> 5, c4 = (idx & 31)*4;
        int gn = n0 + row;
        float4 v = make_float4(0.f,0.f,0.f,0.f);
        if (gn < N) v = *reinterpret_cast<const float4*>(&poi_emb[(size_t)x_idx[gn]*D + c4]);
        unsigned int p0 = (unsigned int)f2bf(v.x) | ((unsigned int)f2bf(v.y) << 16);
        unsigned int p1 = (unsigned int)f2bf(v.z) | ((unsigned int)f2bf(v.w) << 16);
        *reinterpret_cast<uint2*>(&emb[row*136 + c4]) = make_uint2(p0, p1);
    }
    __syncthreads();
    int l = t & 63, w = t >> 6, li = l & 15, q = l >> 4;
    short8 a[4];
    #pragma unroll
    for (int kt = 0; kt < 4; ++kt)
        a[kt] = *reinterpret_cast<const short8*>(&emb[(w*16 + li)*136 + kt*32 + q*8]);
    f32x4 acc[8];
    #pragma unroll
    for (int ct = 0; ct < 8; ++ct) acc[ct] = (f32x4){0.f,0.f,0.f,0.f};
    #pragma unroll
    for (int kt = 0; kt < 4; ++kt){
        #pragma unroll
        for (int ct = 0; ct < 8; ++ct){
            short8 b = reinterpret_cast<const short8*>(wp)[(kt*8 + ct)*64 + l];
            acc[ct] = __builtin_amdgcn_mfma_f32_16x16x32_bf16(a[kt], b, acc[ct], 0, 0, 0);
        }
    }
    __syncthreads();
    #pragma unroll
    for (int ct = 0; ct < 8; ++ct){
        float bias = fc_b[ct*16 + li];
        #pragma unroll
        for (int r = 0; r < 4; ++r){
            float v = acc[ct][r] + bias;
            float s = 1.f/(1.f + __expf(-v));
            emb[(w*16 + q*4 + r)*136 + ct*16 + li] = f2bf(s);
        }
    }
    __syncthreads();
    int row = t >> 2, ch = t & 3, gn = n0 + row;
    if (gn < N){
        #pragma unroll
        for (int i2 = 0; i2 < 4; ++i2){
            uint4 v = *reinterpret_cast<const uint4*>(&emb[row*136 + ch*32 + i2*8]);
            *reinterpret_cast<uint4*>(&x0[(size_t)gn*D + ch*32 + i2*8]) = v;
        }
    }
}

// ---------------- CSR build ----------------
__global__ void count_kernel(const int* __restrict__ dst, int* __restrict__ offsets, int E){
    int e = blockIdx.x*blockDim.x + threadIdx.x;
    if (e < E) atomicAdd(&offsets[dst[e]+1], 1);
}

__global__ void scan1_kernel(int* __restrict__ data, int* __restrict__ bsums, int n){
    __shared__ int wsum[4];
    int base = blockIdx.x * SCAN_TILE + threadIdx.x*4;
    int v[4];
    #pragma unroll
    for (int j=0;j<4;++j) v[j] = (base+j < n) ? data[base+j] : 0;
    v[1]+=v[0]; v[2]+=v[1]; v[3]+=v[2];
    int lane = threadIdx.x & 63;
    int w = threadIdx.x >> 6;
    int s = v[3];
    for (int d=1; d<64; d<<=1){
        int o = __shfl_up(s, d);
        if (lane >= d) s += o;
    }
    if (lane == 63) wsum[w] = s;
    int sexc = s - v[3];
    __syncthreads();
    int woff = 0;
    for (int ww=0; ww<w; ++ww) woff += wsum[ww];
    int off = woff + sexc;
    #pragma unroll
    for (int j=0;j<4;++j) { if (base+j < n) data[base+j] = v[j] + off; }
    if (threadIdx.x == 255) bsums[blockIdx.x] = off + v[3];
}

__global__ void scan2_kernel(int* __restrict__ bsums, int nb){
    __shared__ int ws[4];
    __shared__ int carry_s;
    if (threadIdx.x == 0) carry_s = 0;
    __syncthreads();
    for (int start = 0; start < nb; start += 256){
        int i = start + (int)threadIdx.x;
        int v = (i < nb) ? bsums[i] : 0;
        int lane = threadIdx.x & 63, w = threadIdx.x >> 6;
        int s = v;
        for (int d=1; d<64; d<<=1){ int o = __shfl_up(s, d); if (lane >= d) s += o; }
        if (lane == 63) ws[w] = s;
        __syncthreads();
        int woff = 0;
        for (int ww=0; ww<w; ++ww) woff += ws[ww];
        int inc = s + woff + carry_s;
        if (i < nb) bsums[i] = inc - v;
        __syncthreads();
        if (threadIdx.x == 255) carry_s = inc;
        __syncthreads();
    }
}

__global__ void scan3_kernel(int* __restrict__ data, const int* __restrict__ bsums, int n){
    int base = blockIdx.x * SCAN_TILE + threadIdx.x*4;
    int add = bsums[blockIdx.x];
    #pragma unroll
    for (int j=0;j<4;++j){ if (base+j < n) data[base+j] += add; }
}

__global__ void fill_kernel(const int* __restrict__ src, const int* __restrict__ dst,
                            const int* __restrict__ offsets, int* __restrict__ fillcnt,
                            int* __restrict__ csr, int E){
    int e = blockIdx.x*blockDim.x + threadIdx.x;
    if (e < E){
        int d = dst[e];
        int pos = atomicAdd(&fillcnt[d], 1);
        csr[offsets[d]+pos] = src[e];
    }
}

// ---------------- propagate (bf16): xout[v] = sum_{u->v} xin[u] ----------------
// wave per node; 4 edges per memory instruction (quarter-wave each loads uint4 of one row)
__global__ __launch_bounds__(256) void prop_kernel(const unsigned short* __restrict__ xin,
                            unsigned short* __restrict__ xout,
                            const int* __restrict__ offsets, const int* __restrict__ csr, int N){
    int wid = (blockIdx.x*256 + threadIdx.x) >> 6;
    int lane = threadIdx.x & 63;
    if (wid >= N) return;
    int beg = offsets[wid];
    int end = offsets[wid+1];
    int q = lane >> 4;       // quarter: which edge in group of 4
    int c = lane & 15;       // uint4 chunk within a 128-bf16 row
    float acc[8];
    #pragma unroll
    for (int j=0;j<8;++j) acc[j] = 0.f;
    const uint4* xi4 = (const uint4*)xin;
    for (int base = beg; base < end; base += 64){
        int cnt = min(64, end - base);
        int myu = (base + lane < end) ? csr[base + lane] : 0;
        for (int ei = 0; ei < cnt; ei += 8){
            int eqa = ei + q;
            int ua = __shfl(myu, eqa);
            uint4 va = xi4[(size_t)ua*16 + c];
            bool haveB = (ei + 4) < cnt;
            uint4 vb = make_uint4(0,0,0,0);
            if (haveB){
                int eqb = ei + 4 + q;
                int ub = __shfl(myu, eqb & 63);
                vb = xi4[(size_t)ub*16 + c];
                if (eqb >= cnt){ vb.x = vb.y = vb.z = vb.w = 0; }
            }
            if (eqa >= cnt){ va.x = va.y = va.z = va.w = 0; }
            acc[0] += bf_lo(va.x) + bf_lo(vb.x);
            acc[1] += bf_hi(va.x) + bf_hi(vb.x);
            acc[2] += bf_lo(va.y) + bf_lo(vb.y);
            acc[3] += bf_hi(va.y) + bf_hi(vb.y);
            acc[4] += bf_lo(va.z) + bf_lo(vb.z);
            acc[5] += bf_hi(va.z) + bf_hi(vb.z);
            acc[6] += bf_lo(va.w) + bf_lo(vb.w);
            acc[7] += bf_hi(va.w) + bf_hi(vb.w);
        }
    }
    #pragma unroll
    for (int j=0;j<8;++j){
        acc[j] += __shfl_xor(acc[j], 16);
        acc[j] += __shfl_xor(acc[j], 32);
    }
    if (q == 0){
        uint4 o;
        o.x = (unsigned int)f2bf(acc[0]) | ((unsigned int)f2bf(acc[1]) << 16);
        o.y = (unsigned int)f2bf(acc[2]) | ((unsigned int)f2bf(acc[3]) << 16);
        o.z = (unsigned int)f2bf(acc[4]) | ((unsigned int)f2bf(acc[5]) << 16);
        o.w = (unsigned int)f2bf(acc[6]) | ((unsigned int)f2bf(acc[7]) << 16);
        ((uint4*)xout)[(size_t)wid*16 + c] = o;
    }
}

// ---------------- per-step fused: Y = Z @ X^T (MFMA) -> *y0 -> pooled ----------------
template<int STEP0>
__global__ __launch_bounds__(256) void step_mfma_kernel(const unsigned short* __restrict__ x,
                                 const short* __restrict__ zstep,   // [10][4][64][8] bf16
                                 const int* __restrict__ batch,
                                 uint2* __restrict__ y0buf,         // bf16x4 per entry
                                 float* __restrict__ pooled,        // [B][64]
                                 int N, int stepoff)
{
    __shared__ __align__(16) char lbuf[42240];   // z (40960B) then reused as P[160][66] f32
    __shared__ float accs[64][G_HID];
    __shared__ int slots[64];
    __shared__ int slotb[64];
    __shared__ int nslots_s;
    short* zls = (short*)lbuf;
    float* Pf  = (float*)lbuf;
    int n0 = blockIdx.x * 64;
    int t = threadIdx.x;  // 256

    #pragma unroll
    for (int i = 0; i < 10; ++i)
        ((uint4*)lbuf)[t + i*256] = ((const uint4*)zstep)[t + i*256];
    #pragma unroll
    for (int i = 0; i < 4; ++i) ((float*)accs)[t + i*256] = 0.f;
    if (t < 64) {
        int gn = n0 + t;
        int b = (gn < N) ? batch[gn] : -1;
        int bprev = -1;
        if (t > 0) bprev = (gn-1 < N) ? batch[gn-1] : -1;
        int flag = (t == 0 || b != bprev) ? 1 : 0;
        int s = flag;
        for (int d=1; d<64; d<<=1){ int o = __shfl_up(s, d); if (t >= d) s += o; }
        int slot = s - 1;
        slots[t] = slot;
        if (flag) slotb[slot] = b;
        if (t == 63) nslots_s = s;
    }
    __syncthreads();

    int l = t & 63, w = t >> 6, li = l & 15, q = l >> 4;
    int node = n0 + w*16 + li;
    bool valid = node < N;
    short8 bw[4];
    #pragma unroll
    for (int kt = 0; kt < 4; ++kt){
        if (valid) bw[kt] = *reinterpret_cast<const short8*>(&x[(size_t)node*D + kt*32 + q*8]);
        else       bw[kt] = (short8){0,0,0,0,0,0,0,0};
    }
    f32x4 accA[10];
    #pragma unroll
    for (int t10 = 0; t10 < 10; ++t10){
        f32x4 acc = (f32x4){0.f,0.f,0.f,0.f};
        #pragma unroll
        for (int kt = 0; kt < 4; ++kt){
            short8 az = *reinterpret_cast<const short8*>(&zls[((t10*4 + kt)*64 + l)*8]);
            acc = __builtin_amdgcn_mfma_f32_16x16x32_bf16(az, bw[kt], acc, 0, 0, 0);
        }
        accA[t10] = acc;
    }
    __syncthreads();   // done reading zls; reuse as P

    size_t ybase = ((size_t)blockIdx.x*4 + w)*10*64 + l;
    #pragma unroll
    for (int t10 = 0; t10 < 10; ++t10){
        f32x4 acc = accA[t10];
        float p0, p1, p2, p3;
        if (STEP0){
            uint2 st;
            st.x = (unsigned int)f2bf(acc[0]) | ((unsigned int)f2bf(acc[1]) << 16);
            st.y = (unsigned int)f2bf(acc[2]) | ((unsigned int)f2bf(acc[3]) << 16);
            y0buf[ybase + (size_t)t10*64] = st;
            p0 = acc[0]*acc[0]; p1 = acc[1]*acc[1]; p2 = acc[2]*acc[2]; p3 = acc[3]*acc[3];
        } else {
            uint2 v = y0buf[ybase + (size_t)t10*64];
            p0 = acc[0]*bf_lo(v.x); p1 = acc[1]*bf_hi(v.x);
            p2 = acc[2]*bf_lo(v.y); p3 = acc[3]*bf_hi(v.y);
        }
        int rb = (t10*16 + q*4)*66 + w*16 + li;
        Pf[rb]       = p0;
        Pf[rb + 66]  = p1;
        Pf[rb + 132] = p2;
        Pf[rb + 198] = p3;
    }
    __syncthreads();

    #pragma unroll
    for (int i = 0; i < 4; ++i){
        int g = t & 15, nd = (t >> 4) + i*16;
        float c = 0.f;
        #pragma unroll
        for (int s = 0; s < S_HID; ++s) c += Pf[(g*10 + s)*66 + nd];
        atomicAdd(&accs[slots[nd]][g], c);
    }
    __syncthreads();
    int ns = nslots_s;
    for (int idx = t; idx < ns*G_HID; idx += 256){
        int j = idx >> 4, g = idx & 15;
        int b = slotb[j];
        if (b >= 0) atomicAdd(&pooled[(size_t)b*64 + stepoff + g], accs[j][g]);
    }
}

// ---------------- out = leaky(pooled @ mlp_w + mlp_b) ----------------
__global__ void out_kernel(const float* __restrict__ pooled, const float* __restrict__ mlp_w,
                           const float* __restrict__ mlp_b, float* __restrict__ out, int B){
    __shared__ float row[64];
    int b = blockIdx.x;
    int t = threadIdx.x;  // 128
    if (t < 64) row[t] = pooled[(size_t)b*64 + t];
    __syncthreads();
    float acc = mlp_b[t];
    for (int j=0;j<64;++j) acc += row[j]*mlp_w[j*D + t];
    out[(size_t)b*D + t] = leaky_f(acc);
}

extern "C" void kernel_launch(void* const* d_in, const int* in_sizes, int n_in,
                              void* d_out, int out_size, void* d_ws, size_t ws_size,
                              hipStream_t stream)
{
    const int*   x_idx = (const int*)d_in[0];
    const int*   edge  = (const int*)d_in[1];
    const int*   batch = (const int*)d_in[2];
    const float* poi   = (const float*)d_in[3];
    const float* fc_w  = (const float*)d_in[4];
    const float* fc_b  = (const float*)d_in[5];
    const float* adj   = (const float*)d_in[6];
    const float* feat  = (const float*)d_in[7];
    const float* mlp_w = (const float*)d_in[8];
    const float* mlp_b = (const float*)d_in[9];
    float* out = (float*)d_out;

    int N = in_sizes[0];
    int E = in_sizes[1] / 2;
    int B = out_size / D;
    int sblk = (N + 63) / 64;
    size_t NP = (size_t)sblk * 64;

    char* p = (char*)d_ws;
    auto alloc = [&](size_t bytes)->char* {
        char* r = p;
        p += (bytes + 255) & ~(size_t)255;
        return r;
    };
    unsigned short* x0 = (unsigned short*)alloc(NP*D*2);
    unsigned short* xa = (unsigned short*)alloc(NP*D*2);
    unsigned short* xb = (unsigned short*)alloc(NP*D*2);
    uint2* y0buf       = (uint2*)alloc(NP*160*2);           // bf16 zx in fragment layout
    float* pooled      = (float*)alloc((size_t)B*64*4);
    short* zpack       = (short*)alloc((size_t)MAX_STEP*20480*2);
    short* wp          = (short*)alloc((size_t)16384*2);
    int*   offsets     = (int*)alloc((size_t)(N+1)*4);
    int*   fillcnt     = (int*)alloc((size_t)N*4);
    int*   csr         = (int*)alloc((size_t)E*4);
    int*   bsums       = (int*)alloc(4096);

    const int* srcp = edge;
    const int* dstp = edge + E;

    hipMemsetAsync(offsets, 0, (size_t)(N+1)*4, stream);
    hipMemsetAsync(fillcnt, 0, (size_t)N*4, stream);
    hipMemsetAsync(pooled, 0, (size_t)B*64*4, stream);

    prep_kernel<<<G_HID, 128, 0, stream>>>(adj, feat, zpack);
    wpack_kernel<<<64, 256, 0, stream>>>(fc_w, wp);
    embed_mfma_kernel<<<sblk, 256, 0, stream>>>(x_idx, poi, wp, fc_b, x0, N);

    count_kernel<<<(E+255)/256, 256, 0, stream>>>(dstp, offsets, E);
    int scan_n = N + 1;
    int nblk = (scan_n + SCAN_TILE - 1) / SCAN_TILE;
    scan1_kernel<<<nblk, 256, 0, stream>>>(offsets, bsums, scan_n);
    scan2_kernel<<<1, 256, 0, stream>>>(bsums, nblk);
    scan3_kernel<<<nblk, 256, 0, stream>>>(offsets, bsums, scan_n);
    fill_kernel<<<(E+255)/256, 256, 0, stream>>>(srcp, dstp, offsets, fillcnt, csr, E);

    step_mfma_kernel<1><<<sblk, 256, 0, stream>>>(x0, zpack, batch, y0buf, pooled, N, 0);

    const unsigned short* xin = x0;
    unsigned short* bufs[2] = {xa, xb};
    for (int i = 1; i < MAX_STEP; ++i){
        unsigned short* xout = bufs[(i-1) & 1];
        prop_kernel<<<(N+3)/4, 256, 0, stream>>>(xin, xout, offsets, csr, N);
        step_mfma_kernel<0><<<sblk, 256, 0, stream>>>(xout, zpack + (size_t)i*20480, batch,
                                                      y0buf, pooled, N, i*G_HID);
        xin = xout;
    }
    out_kernel<<<B, D, 0, stream>>>(pooled, mlp_w, mlp_b, out, B);
}